// Round 2
// 140.143 us; speedup vs baseline: 1.1071x; 1.1071x over previous
//
#include <hip/hip_runtime.h>
#include <math.h>

// B=4096, T=64, C=64, H=8, D=8. fp32 in/out.
// d_ws fp16: WqkvT[n][c] (n: q 0-63 | k 64-127 | v 128-191), then W1T[j][c].
// Main kernel: 256 thr (4 waves) per batch element. All-fp16 data path
// (v_cvt_pkrtz packing; fp16 RTZ is more accurate than bf16 RNE here).
// NOTE: half types are __fp16-based: cvt_pkrtz and the MFMA builtins both
// use __fp16 vectors; _Float16 vectors are a clang type-mismatch.
//  phase0: x -> fp16 LDS xs[64][72]       (region0)
//  phase1: QKV^T = Wqkv^T x^T via 16x16x32_f16 MFMA (A=weights, B=x).
//  phase2: per wave, heads 2w,2w+1 with 16x16x16_f16 MFMAs (K=16):
//          A/B frags hold k=4*quad+j  ==  exactly the S^T C-layout, so the
//          packed softmax output IS the PV B-operand: the entire
//          48-bpermute/24-cndmask P-repack network is deleted.
//          S^T col tn: <=4 MFMAs (k zero-padded d=8..15); max-free softmax
//          e = exp2(s * 0.125*log2e); row-sum in-lane + shfl_xor(16,32);
//          O^T col  = sum_km V^T(km) * P(km,tn); normalize by rcp(sum);
//          packed store into qh (att buffer).
//  phase3: y^T = W1^T att^T (16x16x32_f16) -> float4 stores.
// LDS: region0 9216 (xs|vth) + qh 8192 + kh 8192 = 25600 B -> 6 blocks/CU.

typedef __attribute__((ext_vector_type(8))) __fp16 half8;
typedef __attribute__((ext_vector_type(4))) __fp16 half4;
typedef __attribute__((ext_vector_type(2))) __fp16 half2v;
typedef __attribute__((ext_vector_type(4))) float f32x4;

__global__ void prep_weights(const float* __restrict__ Wq,
                             const float* __restrict__ Wk,
                             const float* __restrict__ Wv,
                             const float* __restrict__ W1,
                             __fp16* __restrict__ ws)
{
    int i = blockIdx.x * 256 + threadIdx.x;      // 16384 total
    if (i < 12288) {
        int n = i >> 6, c = i & 63;
        int sec = n >> 6;
        const float* src = (sec == 0) ? Wq : (sec == 1) ? Wk : Wv;
        int h = (n & 63) >> 3, d = n & 7;
        ws[i] = (__fp16)src[h * 512 + c * 8 + d];
    } else {
        int j = (i - 12288) >> 6, c = i & 63;
        ws[i] = (__fp16)W1[c * 64 + j];
    }
}

__device__ __forceinline__ uint32_t pk2h(float a, float b) {
    half2v h = __builtin_amdgcn_cvt_pkrtz(a, b);
    union { half2v h; uint32_t u; } c;
    c.h = h;
    return c.u;
}

__global__ __launch_bounds__(256, 6) void mha_mfma4_kernel(
    const float* __restrict__ x,
    const __fp16* __restrict__ wT,
    const float* __restrict__ b1v,
    float* __restrict__ y)
{
    __shared__ __align__(16) __fp16 region0[64 * 72]; // xs, later vth
    __shared__ __align__(16) __fp16 qh[8 * 64 * 8];   // Q[h][t][d] -> att
    __shared__ __align__(16) __fp16 kh[8 * 64 * 8];   // K[h][s][d]

    __fp16* xs  = region0;            // [64][72]
    __fp16* vth = region0;            // V^T[h][d][s], [64][72] overlay

    const int b    = blockIdx.x;
    const int tid  = threadIdx.x;
    const int lane = tid & 63;
    const int w    = tid >> 6;
    const int l15  = lane & 15;
    const int quad = lane >> 4;

    // ---------------- phase 0: stage x -> fp16 ----------------
    {
        int r = tid >> 2, c0 = (tid & 3) * 16;
        const float* xp = x + (size_t)b * 4096 + r * 64 + c0;
        float4 f0 = ((const float4*)xp)[0];
        float4 f1 = ((const float4*)xp)[1];
        float4 f2 = ((const float4*)xp)[2];
        float4 f3 = ((const float4*)xp)[3];
        union { half2v h2[4]; float4 f; } u0, u1;
        u0.h2[0] = __builtin_amdgcn_cvt_pkrtz(f0.x, f0.y);
        u0.h2[1] = __builtin_amdgcn_cvt_pkrtz(f0.z, f0.w);
        u0.h2[2] = __builtin_amdgcn_cvt_pkrtz(f1.x, f1.y);
        u0.h2[3] = __builtin_amdgcn_cvt_pkrtz(f1.z, f1.w);
        u1.h2[0] = __builtin_amdgcn_cvt_pkrtz(f2.x, f2.y);
        u1.h2[1] = __builtin_amdgcn_cvt_pkrtz(f2.z, f2.w);
        u1.h2[2] = __builtin_amdgcn_cvt_pkrtz(f3.x, f3.y);
        u1.h2[3] = __builtin_amdgcn_cvt_pkrtz(f3.z, f3.w);
        *(float4*)&xs[r * 72 + c0]     = u0.f;
        *(float4*)&xs[r * 72 + c0 + 8] = u1.f;
    }
    __syncthreads();

    // ---------------- phase 1: QKV^T = Wqkv^T x^T ----------------
    {
        half8 xfr[4][2];   // B-frags (x)
        #pragma unroll
        for (int tt = 0; tt < 4; ++tt)
            #pragma unroll
            for (int ks = 0; ks < 2; ++ks)
                xfr[tt][ks] = *(const half8*)&xs[(16 * tt + l15) * 72 + 32 * ks + 8 * quad];
        __syncthreads();    // xs fully consumed; region0 now writable as vth

        #pragma unroll
        for (int i = 0; i < 3; ++i) {
            int mt = 3 * w + i;                       // m-tile over n=0..191
            const __fp16* ap = wT + (16 * mt + l15) * 64 + 8 * quad;
            half8 a0 = *(const half8*)ap;
            half8 a1 = *(const half8*)(ap + 32);
            #pragma unroll
            for (int tt = 0; tt < 4; ++tt) {
                f32x4 acc = {0.f, 0.f, 0.f, 0.f};
                acc = __builtin_amdgcn_mfma_f32_16x16x32_f16(a0, xfr[tt][0], acc, 0, 0, 0);
                acc = __builtin_amdgcn_mfma_f32_16x16x32_f16(a1, xfr[tt][1], acc, 0, 0, 0);
                // thread holds n = 16mt+4quad+r, t = 16tt+l15
                int t = 16 * tt + l15;
                union { uint32_t u2[2]; uint2 u; } pq;
                pq.u2[0] = pk2h(acc[0], acc[1]);
                pq.u2[1] = pk2h(acc[2], acc[3]);
                if (mt < 4) {
                    int hq = 2 * mt + (quad >> 1);
                    *(uint2*)&qh[(hq * 64 + t) * 8 + 4 * (quad & 1)] = pq.u;
                } else if (mt < 8) {
                    int hk = 2 * (mt - 4) + (quad >> 1);
                    *(uint2*)&kh[(hk * 64 + t) * 8 + 4 * (quad & 1)] = pq.u;
                } else {
                    int hv = 2 * (mt - 8) + (quad >> 1);
                    int d0 = 4 * (quad & 1);
                    #pragma unroll
                    for (int r = 0; r < 4; ++r)
                        vth[(hv * 8 + d0 + r) * 72 + t] = (__fp16)acc[r];
                }
            }
        }
    }
    __syncthreads();

    const half4 z4 = {};
    const bool dv = (quad < 2);                      // quads holding valid d (0..7)
    const float SC = 0.125f * 1.4426950408889634f;   // C^-0.5 * log2(e)

    // ---------------- phase 2: attention, heads h = 2w, 2w+1 ----------------
    // 16x16x16_f16: A[m][k]: m=l15, k=4*quad+j.  B[k][n]: n=l15, k=4*quad+j.
    // D[row][col]: row=4*quad+r, col=l15.  S^T output layout == PV B-frag layout.
    #pragma unroll 1
    for (int hh = 0; hh < 2; ++hh) {
        const int h = 2 * w + hh;
        half4 kfr[4], vfr[4];
        #pragma unroll
        for (int tm = 0; tm < 4; ++tm)   // A-frag of K: m=s row, k=d=4q+j (q<2)
            kfr[tm] = dv ? *(const half4*)&kh[(h * 64 + 16 * tm + l15) * 8 + 4 * quad] : z4;
        #pragma unroll
        for (int km = 0; km < 4; ++km)   // A-frag of V^T: m=d=l15 (<8), k=s=16km+4q+j
            vfr[km] = (l15 < 8) ? *(const half4*)&vth[(h * 8 + l15) * 72 + 16 * km + 4 * quad] : z4;

        #pragma unroll
        for (int tn = 0; tn < 4; ++tn) {
            half4 qf = dv ? *(const half4*)&qh[(h * 64 + 16 * tn + l15) * 8 + 4 * quad] : z4;

            f32x4 S[4];   // S^T tiles in column tn, tm <= tn
            #pragma unroll
            for (int tm = 0; tm <= tn; ++tm) {
                f32x4 zz = {0.f, 0.f, 0.f, 0.f};
                S[tm] = __builtin_amdgcn_mfma_f32_16x16x16f16(kfr[tm], qf, zz, 0, 0, 0);
            }

            // max-free softmax (scores bounded): e = exp2(s*SC), causal mask on diag
            float ls = 0.f;
            #pragma unroll
            for (int tm = 0; tm <= tn; ++tm)
                #pragma unroll
                for (int r = 0; r < 4; ++r) {
                    float e = __builtin_exp2f(S[tm][r] * SC);
                    if (tm == tn && (4 * quad + r) > l15) e = 0.f;   // causal
                    S[tm][r] = e;
                    ls += e;
                }
            ls += __shfl_xor(ls, 16);
            ls += __shfl_xor(ls, 32);
            float inv = __builtin_amdgcn_rcpf(ls);

            // O^T col tn: packed P IS the B-frag (k=4q+j == s layout). No shuffle.
            f32x4 O = {0.f, 0.f, 0.f, 0.f};
            #pragma unroll
            for (int km = 0; km <= tn; ++km) {
                union { uint32_t u[2]; half4 h4; } bu;
                bu.u[0] = pk2h(S[km][0], S[km][1]);
                bu.u[1] = pk2h(S[km][2], S[km][3]);
                O = __builtin_amdgcn_mfma_f32_16x16x16f16(vfr[km], bu.h4, O, 0, 0, 0);
            }

            // O^T: row d=4q+r (valid for q<2), col t=16tn+l15; normalize by own column sum
            if (dv) {
                union { uint32_t u2[2]; uint2 u; } po;
                po.u2[0] = pk2h(O[0] * inv, O[1] * inv);
                po.u2[1] = pk2h(O[2] * inv, O[3] * inv);
                *(uint2*)&qh[(h * 64 + 16 * tn + l15) * 8 + 4 * quad] = po.u;
            }
        }
    }
    __syncthreads();

    // ---------------- phase 3: y^T = W1^T att^T ----------------
    {
        const __fp16* wp = wT + 12288 + (16 * w + l15) * 64 + 8 * quad;
        half8 w0 = *(const half8*)wp;
        half8 w1 = *(const half8*)(wp + 32);
        float4 bias4 = *(const float4*)&b1v[16 * w + 4 * quad];
        float* yb = y + (size_t)b * 4096;
        #pragma unroll
        for (int tt = 0; tt < 4; ++tt) {
            half8 bq0 = *(const half8*)&qh[(quad * 64 + 16 * tt + l15) * 8];       // k: h=quad
            half8 bq1 = *(const half8*)&qh[((4 + quad) * 64 + 16 * tt + l15) * 8]; // k: h=4+quad
            f32x4 acc = {0.f, 0.f, 0.f, 0.f};
            acc = __builtin_amdgcn_mfma_f32_16x16x32_f16(w0, bq0, acc, 0, 0, 0);
            acc = __builtin_amdgcn_mfma_f32_16x16x32_f16(w1, bq1, acc, 0, 0, 0);
            float4 o;
            o.x = fmaxf(acc[0] + bias4.x, 0.f);
            o.y = fmaxf(acc[1] + bias4.y, 0.f);
            o.z = fmaxf(acc[2] + bias4.z, 0.f);
            o.w = fmaxf(acc[3] + bias4.w, 0.f);
            *(float4*)&yb[(16 * tt + l15) * 64 + 16 * w + 4 * quad] = o;
        }
    }
}

extern "C" void kernel_launch(void* const* d_in, const int* in_sizes, int n_in,
                              void* d_out, int out_size, void* d_ws, size_t ws_size,
                              hipStream_t stream) {
    const float* x  = (const float*)d_in[0];
    const float* Wq = (const float*)d_in[1];
    const float* Wk = (const float*)d_in[2];
    const float* Wv = (const float*)d_in[3];
    const float* W1 = (const float*)d_in[4];
    const float* b1 = (const float*)d_in[5];
    float* y = (float*)d_out;
    __fp16* ws = (__fp16*)d_ws;

    const int B = in_sizes[0] / 4096;   // 4096
    prep_weights<<<64, 256, 0, stream>>>(Wq, Wk, Wv, W1, ws);
    mha_mfma4_kernel<<<B, 256, 0, stream>>>(x, ws, b1, y);
}